// Round 11
// baseline (156.573 us; speedup 1.0000x reference)
//
#include <hip/hip_runtime.h>
#include <hip/hip_fp16.h>
#include <math.h>

// ---- problem constants (match reference) ----
#define NCOLS   407
#define RAD_OFF 87
#define ANG_OFF 151
#define T1      3072    // items per sort tile
#define WB      32      // atoms per bucket (bucket = atom>>5)
#define MAXBKT  640     // max buckets supported (n_atoms <= 20480)
#define CAP2    3008    // pass2 per-bucket LDS capacity (mean ~1000, +60 sigma)

// shiftR[r] = 0.8 + r*0.275  (r=0..15)
// shiftA[a] = 0.8 + a*0.675  (a=0..3)
// shiftZ[z] = pi/8 + z*pi/4  (z=0..3)

typedef __attribute__((ext_vector_type(8))) _Float16 f16x8;
typedef __attribute__((ext_vector_type(4))) float    f32x4;

static __device__ inline unsigned pack2(float a, float b) {
    __half2 h = __floats2half2_rn(a, b);
    return *reinterpret_cast<unsigned*>(&h);
}
static __device__ inline float2 unpack2(unsigned u) {
    __half2 h = *reinterpret_cast<__half2*>(&u);
    return __half22float2(h);
}

// ============ init: per-atom valence table ============
__global__ __launch_bounds__(256) void init_kernel(const int* __restrict__ species,
                                                   const float4* __restrict__ valence,
                                                   float4* __restrict__ val_atom,
                                                   int n_atoms) {
    int idx = blockIdx.x * 256 + threadIdx.x;
    if (idx < n_atoms) val_atom[idx] = valence[species[idx]];
}

// ============ pass0: per-tile bucket histogram (keys only) + edata build ============
// blocks [0, nt_rad): radial tiles; [nt_rad, nt_rad+nt_ang): angular tiles; rest: edata
__global__ __launch_bounds__(256) void pass0_kernel(const int* __restrict__ esrc,
                                                    const int* __restrict__ central,
                                                    const float* __restrict__ ang_dist,
                                                    const float* __restrict__ ang_sw,
                                                    const int* __restrict__ ang_edge_dst,
                                                    const float4* __restrict__ val_atom,
                                                    int* __restrict__ tileHist,
                                                    uint4* __restrict__ edata,
                                                    int n_edges, int n_pairs, int n_ang_edges,
                                                    int nbkt, int nt_rad, int nt_ang) {
    int bid = blockIdx.x;
    int t = threadIdx.x;

    if (bid < nt_rad + nt_ang) {
        __shared__ int lh[MAXBKT];
        int is_ang = bid >= nt_rad;
        const int* key = is_ang ? central : esrc;
        int n   = is_ang ? n_pairs : n_edges;
        int off = (is_ang ? bid - nt_rad : bid) * T1;
        for (int b = t; b < nbkt; b += 256) lh[b] = 0;
        __syncthreads();
        #pragma unroll
        for (int k = 0; k < T1 / 256; ++k) {
            int i = off + k * 256 + t;
            if (i < n) atomicAdd(&lh[key[i] >> 5], 1);
        }
        __syncthreads();
        int* row = tileHist + (size_t)bid * nbkt;
        for (int b = t; b < nbkt; b += 256) row[b] = lh[b];
        return;
    }

    // ---- edata blocks: 2560 edges each ----
    int i = (bid - nt_rad - nt_ang) * 2560 + t;
    #pragma unroll
    for (int k = 0; k < 10; ++k, i += 256) {
        if (i < n_ang_edges) {
            float4 v = val_atom[ang_edge_dst[i]];
            uint4 r;
            r.x = __float_as_uint(ang_dist[i]);
            r.y = __float_as_uint(ang_sw[i]);
            r.z = pack2(v.x, v.y);
            r.w = pack2(v.z, v.w);
            edata[i] = r;
        }
    }
}

// ============ scan05: tileHist -> global run bases (in place) + bucketBase ============
// block 0 = radial rows [0,nt_rad), block 1 = angular rows [nt_rad, nt_rad+nt_ang)
__global__ __launch_bounds__(1024) void scan05_kernel(int* __restrict__ tileHist,
                                                      int* __restrict__ bktBase,
                                                      int nt_rad, int nt_ang, int nbkt) {
    int g = blockIdx.x;
    int* th = tileHist + (g ? (size_t)nt_rad * nbkt : 0);
    int nt = g ? nt_ang : nt_rad;
    int* bb = bktBase + g * (MAXBKT + 1);
    __shared__ int part[1024];
    int t = threadIdx.x;
    int total = 0;
    if (t < nbkt)
        for (int k = 0; k < nt; ++k) total += th[(size_t)k * nbkt + t];
    part[t] = (t < nbkt) ? total : 0;
    __syncthreads();
    for (int off = 1; off < 1024; off <<= 1) {
        int v = (t >= off) ? part[t - off] : 0;
        __syncthreads();
        part[t] += v;
        __syncthreads();
    }
    if (t < nbkt) {
        int base = part[t] - total;   // exclusive
        bb[t] = base;
        int run = base;
        for (int k = 0; k < nt; ++k) {
            int tmp = th[(size_t)k * nbkt + t];
            th[(size_t)k * nbkt + t] = run;
            run += tmp;
        }
        if (t == nbkt - 1) bb[nbkt] = run;
    }
}

// ============ pass1: compute records + LDS bucket-reorder + COALESCED store ============
// records: radial {f32 d, half2 ps*v01, half2 ps*v23, atom}; angular {e1, e2, ang, atom}
__global__ __launch_bounds__(256) void pass1_kernel(
    const float* __restrict__ dist, const float* __restrict__ sw,
    const int* __restrict__ esrc, const int* __restrict__ edst,
    const float* __restrict__ ang_angles,
    const int* __restrict__ psrc, const int* __restrict__ pdst,
    const int* __restrict__ central,
    const float4* __restrict__ val_atom,
    const int* __restrict__ tileHist,
    uint4* __restrict__ arr_rad, uint4* __restrict__ arr_ang,
    int n_edges, int n_pairs, int nbkt, int nt_rad)
{
    __shared__ uint4 buf[T1];        // 48 KB
    __shared__ int   dst[T1];        // 12 KB
    __shared__ int   lh[MAXBKT];     // counts -> exclusive scan
    __shared__ int   gb[MAXBKT];     // global run bases for this tile
    __shared__ int   sc[256];

    int bid = blockIdx.x;
    int t = threadIdx.x;
    int is_ang = bid >= nt_rad;
    const int* key = is_ang ? central : esrc;
    int n   = is_ang ? n_pairs : n_edges;
    int off = (is_ang ? bid - nt_rad : bid) * T1;
    int cnt = min(T1, n - off);
    uint4* arr = is_ang ? arr_ang : arr_rad;
    const int* throw_ = tileHist + (size_t)bid * nbkt;

    for (int b = t; b < nbkt; b += 256) { lh[b] = 0; gb[b] = throw_[b]; }
    __syncthreads();

    // loop 1: ranks
    int meta[T1 / 256];              // b*4096 + rank
    #pragma unroll
    for (int k = 0; k < T1 / 256; ++k) {
        int i = off + k * 256 + t;
        meta[k] = -1;
        if (i < n) {
            int b = key[i] >> 5;
            int r = atomicAdd(&lh[b], 1);
            meta[k] = (b << 12) | r;
        }
    }
    __syncthreads();

    // exclusive scan of lh[0..nbkt)
    {
        int ch = (nbkt + 255) >> 8;  // <=3 for nbkt<=640 handled; support up to 4
        int vals[4];
        int lo = t * ch, s = 0;
        for (int k = 0; k < ch; ++k) {
            int idx = lo + k;
            int v = (idx < nbkt) ? lh[idx] : 0;
            vals[k] = v; s += v;
        }
        sc[t] = s;
        __syncthreads();
        for (int o = 1; o < 256; o <<= 1) {
            int v = (t >= o) ? sc[t - o] : 0;
            __syncthreads();
            sc[t] += v;
            __syncthreads();
        }
        int run = sc[t] - s;
        for (int k = 0; k < ch; ++k) {
            int idx = lo + k;
            if (idx < nbkt) lh[idx] = run;
            run += vals[k];
        }
        __syncthreads();
    }

    // loop 2: build records, place into LDS at bucket-sorted position
    #pragma unroll
    for (int k = 0; k < T1 / 256; ++k) {
        if (meta[k] < 0) continue;
        int i = off + k * 256 + t;
        int b = meta[k] >> 12, r = meta[k] & 4095;
        uint4 rec;
        if (!is_ang) {
            float d  = dist[i];
            float ps = 0.25f * sw[i];
            float4 v = val_atom[edst[i]];
            rec.x = __float_as_uint(d);
            rec.y = pack2(ps * v.x, ps * v.y);
            rec.z = pack2(ps * v.z, ps * v.w);
            rec.w = (unsigned)esrc[i];
        } else {
            rec.x = (unsigned)psrc[i];
            rec.y = (unsigned)pdst[i];
            rec.z = __float_as_uint(ang_angles[i]);
            rec.w = (unsigned)central[i];
        }
        int pos = lh[b] + r;
        buf[pos] = rec;
        dst[pos] = gb[b] + r;        // consecutive within each bucket run
    }
    __syncthreads();

    // loop 3: coalesced writer (dst consecutive within runs)
    #pragma unroll
    for (int k = 0; k < T1 / 256; ++k) {
        int j = k * 256 + t;
        if (j < cnt) arr[dst[j]] = buf[j];
    }
}

// ============ pass2: per-bucket in-place sort by atom + offsets ============
__global__ __launch_bounds__(256) void pass2_kernel(uint4* __restrict__ arr_rad,
                                                    uint4* __restrict__ arr_ang,
                                                    const int* __restrict__ bktBase,
                                                    int* __restrict__ rad_offsets,
                                                    int* __restrict__ ang_offsets,
                                                    int nbkt, int n_atoms) {
    __shared__ uint4  buf[CAP2];     // 48.1 KB
    __shared__ unsigned short rnk[CAP2];
    __shared__ int lh[WB];
    __shared__ int scanA[WB + 1];

    int bid = blockIdx.x;
    int t = threadIdx.x;
    int g = bid >= nbkt;
    int b = g ? bid - nbkt : bid;
    const int* bb = bktBase + g * (MAXBKT + 1);
    int lo = bb[b], hi = bb[b + 1];
    int cnt = hi - lo;                       // expected <= ~1200 << CAP2
    uint4* arr = g ? arr_ang : arr_rad;
    int* offsets = g ? ang_offsets : rad_offsets;
    int loA = b << 5;

    if (t < WB) lh[t] = 0;
    __syncthreads();
    for (int j = t; j < cnt; j += 256) {
        uint4 r = arr[lo + j];
        buf[j] = r;
        int a = (int)r.w - loA;
        rnk[j] = (unsigned short)atomicAdd(&lh[a], 1);
    }
    __syncthreads();
    if (t == 0) {
        int run = 0;
        for (int a = 0; a < WB; ++a) { scanA[a] = run; run += lh[a]; }
        scanA[WB] = run;
    }
    __syncthreads();
    if (t < WB && loA + t < n_atoms) offsets[loA + t] = lo + scanA[t];
    if (t == 0 && b == nbkt - 1) offsets[n_atoms] = bb[nbkt];
    for (int j = t; j < cnt; j += 256) {
        int a = (int)buf[j].w - loA;
        arr[lo + scanA[a] + (int)rnk[j]] = buf[j];   // scattered but L2-hot region
    }
}

// ============ phase B: one wave per atom (unchanged from R9) ============
__global__ __launch_bounds__(256) void phaseB_kernel(
    const uint4* __restrict__ ang_rec, const int* __restrict__ ang_offsets,
    const uint4* __restrict__ edata,
    const uint4* __restrict__ rad_pay, const int* __restrict__ rad_offsets,
    const int* __restrict__ species,
    float* __restrict__ out, int n_atoms)
{
    __shared__ uint4 sh[4][256];      // 4KB per wave, wave-private
    int wid  = (blockIdx.x << 2) + (threadIdx.x >> 6);
    int lane = threadIdx.x & 63;
    uint4* my = sh[threadIdx.x >> 6];

    if (wid < n_atoms) {
        // ---------------- angular (MFMA) ----------------
        int atom = wid;
        int beg = ang_offsets[atom];
        int end = ang_offsets[atom + 1];
        int m  = lane & 15;
        int g4 = lane >> 4;
        const _Float16* hl = (const _Float16*)my;
        f32x4 acc = {0.f, 0.f, 0.f, 0.f};

        for (int base = beg; base < end; base += 64) {
            int idx = base + lane;
            unsigned q[16];
            if (idx < end) {
                uint4 pr = ang_rec[idx];
                int e1 = (int)pr.x;
                int e2 = (int)pr.y;
                float ang = __uint_as_float(pr.z);
                uint4 r1 = edata[e1];
                uint4 r2 = edata[e2];
                float d12 = 0.5f * (__uint_as_float(r1.x) + __uint_as_float(r2.x));
                float swp = 2.0f * __uint_as_float(r1.y) * __uint_as_float(r2.y);
                float2 v1a = unpack2(r1.z), v1b = unpack2(r1.w);
                float2 v2a = unpack2(r2.z), v2b = unpack2(r2.w);
                float vp[4] = {v1a.x + v2a.x, v1a.y + v2a.y, v1b.x + v2b.x, v1b.y + v2b.y};
                float vm[4] = {v1a.x * v2a.x, v1a.y * v2a.y, v1b.x * v2b.x, v1b.y * v2b.y};

                float sa, ca;
                __sincosf(ang, &sa, &ca);
                const float czv[4] = { 0.92387953f,  0.38268343f, -0.38268343f, -0.92387953f };
                const float szv[4] = { 0.38268343f,  0.92387953f,  0.92387953f,  0.38268343f };
                float f1v[4];
                #pragma unroll
                for (int z = 0; z < 4; ++z) {
                    float y = 0.5f + 0.5f * (ca * czv[z] + sa * szv[z]);
                    float y2 = y * y, y4 = y2 * y2, y8 = y4 * y4, y16 = y8 * y8;
                    f1v[z] = y16 * y16;
                }
                float f2sv[4];
                #pragma unroll
                for (int a = 0; a < 4; ++a) {
                    float x = d12 - (0.8f + 0.675f * (float)a);
                    f2sv[a] = swp * __expf(-8.0f * x * x);
                }
                #pragma unroll
                for (int a = 0; a < 4; ++a) {
                    q[a * 2 + 0] = pack2(f2sv[a] * f1v[0], f2sv[a] * f1v[1]);
                    q[a * 2 + 1] = pack2(f2sv[a] * f1v[2], f2sv[a] * f1v[3]);
                }
                #pragma unroll
                for (int i2 = 0; i2 < 4; ++i2) {
                    q[8 + i2 * 2 + 0] = pack2(vp[i2] * vm[0], vp[i2] * vm[1]);
                    q[8 + i2 * 2 + 1] = pack2(vp[i2] * vm[2], vp[i2] * vm[3]);
                }
            } else {
                #pragma unroll
                for (int k = 0; k < 16; ++k) q[k] = 0u;
            }
            my[lane * 4 + 0] = make_uint4(q[0],  q[1],  q[2],  q[3]);
            my[lane * 4 + 1] = make_uint4(q[4],  q[5],  q[6],  q[7]);
            my[lane * 4 + 2] = make_uint4(q[8],  q[9],  q[10], q[11]);
            my[lane * 4 + 3] = make_uint4(q[12], q[13], q[14], q[15]);
            asm volatile("s_waitcnt lgkmcnt(0)" ::: "memory");

            int cnt = min(64, end - base);
            {
                f16x8 wf, uf;
                #pragma unroll
                for (int i = 0; i < 8; ++i) {
                    int row = (g4 << 3) + i;
                    wf[i] = hl[row * 32 + m];
                    uf[i] = hl[row * 32 + 16 + m];
                }
                acc = __builtin_amdgcn_mfma_f32_16x16x32_f16(wf, uf, acc, 0, 0, 0);
            }
            if (cnt > 32) {
                f16x8 wf, uf;
                #pragma unroll
                for (int i = 0; i < 8; ++i) {
                    int row = 32 + (g4 << 3) + i;
                    wf[i] = hl[row * 32 + m];
                    uf[i] = hl[row * 32 + 16 + m];
                }
                acc = __builtin_amdgcn_mfma_f32_16x16x32_f16(wf, uf, acc, 0, 0, 0);
            }
            asm volatile("s_waitcnt lgkmcnt(0)" ::: "memory");
        }
        // C/D layout (m89-verified): col = lane&15, row = (lane>>4)*4 + reg
        float* orow = out + (size_t)atom * NCOLS + ANG_OFF;
        #pragma unroll
        for (int r = 0; r < 4; ++r)
            orow[(g4 * 4 + r) * 16 + m] = acc[r];
        return;
    }

    // ---------------- radial + onehot ----------------
    int atom = wid - n_atoms;
    if (atom >= n_atoms) return;
    int beg = rad_offsets[atom];
    int end = rad_offsets[atom + 1];
    int r = lane >> 2, k = lane & 3;
    float shift = 0.8f + 0.275f * (float)r;
    float acc = 0.0f;
    for (int base = beg; base < end; base += 64) {
        int idx = base + lane;
        if (idx < end) my[lane] = rad_pay[idx];
        asm volatile("s_waitcnt lgkmcnt(0)" ::: "memory");
        int cnt = min(64, end - base);
        for (int e = 0; e < cnt; ++e) {
            uint4 rec = my[e];
            float d = __uint_as_float(rec.x);
            float2 f01 = unpack2(rec.y);
            float2 f23 = unpack2(rec.z);
            float pv = (k == 0) ? f01.x : (k == 1) ? f01.y : (k == 2) ? f23.x : f23.y;
            float x = d - shift;
            acc += __expf(-16.0f * x * x) * pv;
        }
        asm volatile("s_waitcnt lgkmcnt(0)" ::: "memory");
    }
    size_t rowbase = (size_t)atom * NCOLS;
    out[rowbase + RAD_OFF + lane] = acc;
    int sp = species[atom];
    out[rowbase + lane] = (lane == sp) ? 1.0f : 0.0f;
    if (lane < 23) out[rowbase + 64 + lane] = ((64 + lane) == sp) ? 1.0f : 0.0f;
}

extern "C" void kernel_launch(void* const* d_in, const int* in_sizes, int n_in,
                              void* d_out, int out_size, void* d_ws, size_t ws_size,
                              hipStream_t stream) {
    const int*   species      = (const int*)  d_in[0];
    const float* distances    = (const float*)d_in[1];
    const float* switch_      = (const float*)d_in[2];
    const int*   edge_src     = (const int*)  d_in[3];
    const int*   edge_dst     = (const int*)  d_in[4];
    const float* ang_angles   = (const float*)d_in[5];
    const float* ang_dist     = (const float*)d_in[6];
    const float* ang_switch   = (const float*)d_in[7];
    const int*   ang_edge_dst = (const int*)  d_in[8];
    const int*   angle_src    = (const int*)  d_in[9];
    const int*   angle_dst    = (const int*)  d_in[10];
    const int*   central_atom = (const int*)  d_in[11];
    const float4* valence     = (const float4*)d_in[12];

    float* out = (float*)d_out;

    const int n_atoms     = in_sizes[0];
    const int n_edges     = in_sizes[1];
    const int n_ang_edges = in_sizes[6];
    const int n_pairs     = in_sizes[5];

    const int nbkt   = (n_atoms + WB - 1) / WB;       // 625 (<= MAXBKT)
    const int nt_rad = (n_edges + T1 - 1) / T1;       // 209
    const int nt_ang = (n_pairs + T1 - 1) / T1;       // 183

    // ---- workspace layout (16B-aligned), total ~= 23.3 MB ----
    char* ws = (char*)d_ws;
    size_t off = 0;
    auto alloc = [&](size_t bytes) -> void* {
        void* p = ws + off;
        off = (off + bytes + 15) & ~(size_t)15;
        return p;
    };
    uint4*  arr_rad     = (uint4*) alloc((size_t)n_edges * 16);                     // 10.24 MB
    uint4*  arr_ang     = (uint4*) alloc((size_t)n_pairs * 16);                     //  8.96 MB
    uint4*  edata       = (uint4*) alloc((size_t)n_ang_edges * 16);                 //  2.56 MB
    int*    tileHist    = (int*)   alloc((size_t)(nt_rad + nt_ang) * nbkt * 4);     //  0.98 MB
    int*    bktBase     = (int*)   alloc((size_t)2 * (MAXBKT + 1) * sizeof(int));
    float4* val_atom    = (float4*)alloc((size_t)n_atoms * sizeof(float4));         //  0.32 MB
    int*    rad_offsets = (int*)   alloc((size_t)(n_atoms + 1) * sizeof(int));
    int*    ang_offsets = (int*)   alloc((size_t)(n_atoms + 1) * sizeof(int));

    init_kernel<<<(n_atoms + 255) / 256, 256, 0, stream>>>(
        species, valence, val_atom, n_atoms);

    int nb_edata = (n_ang_edges + 2559) / 2560;
    pass0_kernel<<<nt_rad + nt_ang + nb_edata, 256, 0, stream>>>(
        edge_src, central_atom, ang_dist, ang_switch, ang_edge_dst, val_atom,
        tileHist, edata, n_edges, n_pairs, n_ang_edges, nbkt, nt_rad, nt_ang);

    scan05_kernel<<<2, 1024, 0, stream>>>(tileHist, bktBase, nt_rad, nt_ang, nbkt);

    pass1_kernel<<<nt_rad + nt_ang, 256, 0, stream>>>(
        distances, switch_, edge_src, edge_dst,
        ang_angles, angle_src, angle_dst, central_atom,
        val_atom, tileHist, arr_rad, arr_ang,
        n_edges, n_pairs, nbkt, nt_rad);

    pass2_kernel<<<2 * nbkt, 256, 0, stream>>>(
        arr_rad, arr_ang, bktBase, rad_offsets, ang_offsets, nbkt, n_atoms);

    int nb_B = (2 * n_atoms + 3) / 4;    // 4 waves/block, 1 atom per wave
    phaseB_kernel<<<nb_B, 256, 0, stream>>>(
        arr_ang, ang_offsets, edata, arr_rad, rad_offsets, species, out, n_atoms);
}

// Round 12
// 90.110 us; speedup vs baseline: 1.7376x; 1.7376x over previous
//
#include <hip/hip_runtime.h>
#include <hip/hip_fp16.h>
#include <math.h>

// ---- problem constants (match reference) ----
#define NCOLS   407
#define RAD_OFF 87
#define ANG_OFF 151
#define T1      3072    // items per sort tile
#define WB      32      // atoms per bucket (bucket = atom>>5)
#define MAXBKT  640     // max buckets supported (n_atoms <= 20480)
#define CAP2    3008    // pass2 per-bucket LDS capacity (mean ~1000, +60 sigma)

// shiftR[r] = 0.8 + r*0.275  (r=0..15)
// shiftA[a] = 0.8 + a*0.675  (a=0..3)
// shiftZ[z] = pi/8 + z*pi/4  (z=0..3)

typedef __attribute__((ext_vector_type(8))) _Float16 f16x8;
typedef __attribute__((ext_vector_type(4))) float    f32x4;

static __device__ inline unsigned pack2(float a, float b) {
    __half2 h = __floats2half2_rn(a, b);
    return *reinterpret_cast<unsigned*>(&h);
}
static __device__ inline float2 unpack2(unsigned u) {
    __half2 h = *reinterpret_cast<__half2*>(&u);
    return __half22float2(h);
}

// ============ init: per-atom valence table ============
__global__ __launch_bounds__(256) void init_kernel(const int* __restrict__ species,
                                                   const float4* __restrict__ valence,
                                                   float4* __restrict__ val_atom,
                                                   int n_atoms) {
    int idx = blockIdx.x * 256 + threadIdx.x;
    if (idx < n_atoms) val_atom[idx] = valence[species[idx]];
}

// ============ pass0: per-tile bucket histogram (keys only) + edata build ============
__global__ __launch_bounds__(256) void pass0_kernel(const int* __restrict__ esrc,
                                                    const int* __restrict__ central,
                                                    const float* __restrict__ ang_dist,
                                                    const float* __restrict__ ang_sw,
                                                    const int* __restrict__ ang_edge_dst,
                                                    const float4* __restrict__ val_atom,
                                                    int* __restrict__ tileHist,
                                                    uint4* __restrict__ edata,
                                                    int n_edges, int n_pairs, int n_ang_edges,
                                                    int nbkt, int nt_rad, int nt_ang) {
    int bid = blockIdx.x;
    int t = threadIdx.x;

    if (bid < nt_rad + nt_ang) {
        __shared__ int lh[MAXBKT];
        int is_ang = bid >= nt_rad;
        const int* key = is_ang ? central : esrc;
        int n   = is_ang ? n_pairs : n_edges;
        int off = (is_ang ? bid - nt_rad : bid) * T1;
        for (int b = t; b < nbkt; b += 256) lh[b] = 0;
        __syncthreads();
        #pragma unroll
        for (int k = 0; k < T1 / 256; ++k) {
            int i = off + k * 256 + t;
            if (i < n) atomicAdd(&lh[key[i] >> 5], 1);
        }
        __syncthreads();
        int* row = tileHist + (size_t)bid * nbkt;
        for (int b = t; b < nbkt; b += 256) row[b] = lh[b];
        return;
    }

    // ---- edata blocks: 2560 edges each ----
    int i = (bid - nt_rad - nt_ang) * 2560 + t;
    #pragma unroll
    for (int k = 0; k < 10; ++k, i += 256) {
        if (i < n_ang_edges) {
            float4 v = val_atom[ang_edge_dst[i]];
            uint4 r;
            r.x = __float_as_uint(ang_dist[i]);
            r.y = __float_as_uint(ang_sw[i]);
            r.z = pack2(v.x, v.y);
            r.w = pack2(v.z, v.w);
            edata[i] = r;
        }
    }
}

// ============ scanA: one WAVE per (graph,bucket): in-place local prefix + totals ============
__global__ __launch_bounds__(256) void scanA_kernel(int* __restrict__ tileHist,
                                                    int* __restrict__ bktTotals,
                                                    int nt_rad, int nt_ang, int nbkt) {
    int wid  = blockIdx.x * 4 + (threadIdx.x >> 6);
    int lane = threadIdx.x & 63;
    if (wid >= 2 * nbkt) return;
    int g = wid >= nbkt;
    int b = g ? wid - nbkt : wid;
    int* th = tileHist + (g ? (size_t)nt_rad * nbkt : 0);
    int nt = g ? nt_ang : nt_rad;
    int run = 0;
    for (int k0 = 0; k0 < nt; k0 += 64) {
        int k = k0 + lane;
        int v = (k < nt) ? th[(size_t)k * nbkt + b] : 0;
        int s = v;
        #pragma unroll
        for (int o = 1; o < 64; o <<= 1) {
            int u = __shfl_up(s, o, 64);
            if (lane >= o) s += u;
        }
        if (k < nt) th[(size_t)k * nbkt + b] = run + s - v;   // bucket-local exclusive
        run += __shfl(s, 63, 64);
    }
    if (lane == 0) bktTotals[g * MAXBKT + b] = run;
}

// ============ scanB: exclusive scan over buckets -> bktBase ============
__global__ __launch_bounds__(1024) void scanB_kernel(const int* __restrict__ bktTotals,
                                                     int* __restrict__ bktBase, int nbkt) {
    int g = blockIdx.x;
    const int* tot = bktTotals + g * MAXBKT;
    int* bb = bktBase + g * (MAXBKT + 1);
    __shared__ int part[1024];
    int t = threadIdx.x;
    int v = (t < nbkt) ? tot[t] : 0;
    part[t] = v;
    __syncthreads();
    for (int o = 1; o < 1024; o <<= 1) {
        int u = (t >= o) ? part[t - o] : 0;
        __syncthreads();
        part[t] += u;
        __syncthreads();
    }
    if (t < nbkt) bb[t] = part[t] - v;
    if (t == nbkt - 1) bb[nbkt] = part[t];
}

// ============ pass1: compute records + LDS bucket-reorder + COALESCED store ============
__global__ __launch_bounds__(256) void pass1_kernel(
    const float* __restrict__ dist, const float* __restrict__ sw,
    const int* __restrict__ esrc, const int* __restrict__ edst,
    const float* __restrict__ ang_angles,
    const int* __restrict__ psrc, const int* __restrict__ pdst,
    const int* __restrict__ central,
    const float4* __restrict__ val_atom,
    const int* __restrict__ tileHist, const int* __restrict__ bktBase,
    uint4* __restrict__ arr_rad, uint4* __restrict__ arr_ang,
    int n_edges, int n_pairs, int nbkt, int nt_rad)
{
    __shared__ uint4 buf[T1];        // 48 KB
    __shared__ int   dst[T1];        // 12 KB
    __shared__ int   lh[MAXBKT];     // counts -> exclusive scan
    __shared__ int   gb[MAXBKT];     // global run bases for this tile
    __shared__ int   sc[256];

    int bid = blockIdx.x;
    int t = threadIdx.x;
    int is_ang = bid >= nt_rad;
    const int* key = is_ang ? central : esrc;
    int n   = is_ang ? n_pairs : n_edges;
    int off = (is_ang ? bid - nt_rad : bid) * T1;
    int cnt = min(T1, n - off);
    uint4* arr = is_ang ? arr_ang : arr_rad;
    const int* row = tileHist + (size_t)bid * nbkt;
    const int* bb  = bktBase + is_ang * (MAXBKT + 1);

    for (int b = t; b < nbkt; b += 256) { lh[b] = 0; gb[b] = row[b] + bb[b]; }
    __syncthreads();

    // loop 1: ranks
    int meta[T1 / 256];              // b*4096 + rank
    #pragma unroll
    for (int k = 0; k < T1 / 256; ++k) {
        int i = off + k * 256 + t;
        meta[k] = -1;
        if (i < n) {
            int b = key[i] >> 5;
            int r = atomicAdd(&lh[b], 1);
            meta[k] = (b << 12) | r;
        }
    }
    __syncthreads();

    // exclusive scan of lh[0..nbkt)
    {
        int ch = (nbkt + 255) >> 8;
        int vals[4];
        int lo = t * ch, s = 0;
        for (int k = 0; k < ch; ++k) {
            int idx = lo + k;
            int v = (idx < nbkt) ? lh[idx] : 0;
            vals[k] = v; s += v;
        }
        sc[t] = s;
        __syncthreads();
        for (int o = 1; o < 256; o <<= 1) {
            int v = (t >= o) ? sc[t - o] : 0;
            __syncthreads();
            sc[t] += v;
            __syncthreads();
        }
        int run = sc[t] - s;
        for (int k = 0; k < ch; ++k) {
            int idx = lo + k;
            if (idx < nbkt) lh[idx] = run;
            run += vals[k];
        }
        __syncthreads();
    }

    // loop 2: build records, place into LDS at bucket-sorted position
    #pragma unroll
    for (int k = 0; k < T1 / 256; ++k) {
        if (meta[k] < 0) continue;
        int i = off + k * 256 + t;
        int b = meta[k] >> 12, r = meta[k] & 4095;
        uint4 rec;
        if (!is_ang) {
            float d  = dist[i];
            float ps = 0.25f * sw[i];
            float4 v = val_atom[edst[i]];
            rec.x = __float_as_uint(d);
            rec.y = pack2(ps * v.x, ps * v.y);
            rec.z = pack2(ps * v.z, ps * v.w);
            rec.w = (unsigned)esrc[i];
        } else {
            rec.x = (unsigned)psrc[i];
            rec.y = (unsigned)pdst[i];
            rec.z = __float_as_uint(ang_angles[i]);
            rec.w = (unsigned)central[i];
        }
        int pos = lh[b] + r;
        buf[pos] = rec;
        dst[pos] = gb[b] + r;        // consecutive within each bucket run
    }
    __syncthreads();

    // loop 3: coalesced writer (dst consecutive within runs)
    #pragma unroll
    for (int k = 0; k < T1 / 256; ++k) {
        int j = k * 256 + t;
        if (j < cnt) arr[dst[j]] = buf[j];
    }
}

// ============ pass2: per-bucket in-place sort by atom + offsets ============
__global__ __launch_bounds__(256) void pass2_kernel(uint4* __restrict__ arr_rad,
                                                    uint4* __restrict__ arr_ang,
                                                    const int* __restrict__ bktBase,
                                                    int* __restrict__ rad_offsets,
                                                    int* __restrict__ ang_offsets,
                                                    int nbkt, int n_atoms) {
    __shared__ uint4  buf[CAP2];     // 48.1 KB
    __shared__ unsigned short rnk[CAP2];
    __shared__ int lh[WB];
    __shared__ int scanA_[WB + 1];

    int bid = blockIdx.x;
    int t = threadIdx.x;
    int g = bid >= nbkt;
    int b = g ? bid - nbkt : bid;
    const int* bb = bktBase + g * (MAXBKT + 1);
    int lo = bb[b], hi = bb[b + 1];
    int cnt = hi - lo;
    uint4* arr = g ? arr_ang : arr_rad;
    int* offsets = g ? ang_offsets : rad_offsets;
    int loA = b << 5;

    if (t < WB) lh[t] = 0;
    __syncthreads();
    for (int j = t; j < cnt; j += 256) {
        uint4 r = arr[lo + j];
        buf[j] = r;
        int a = (int)r.w - loA;
        rnk[j] = (unsigned short)atomicAdd(&lh[a], 1);
    }
    __syncthreads();
    if (t == 0) {
        int run = 0;
        for (int a = 0; a < WB; ++a) { scanA_[a] = run; run += lh[a]; }
        scanA_[WB] = run;
    }
    __syncthreads();
    if (t < WB && loA + t < n_atoms) offsets[loA + t] = lo + scanA_[t];
    if (t == 0 && b == nbkt - 1) offsets[n_atoms] = bb[nbkt];
    for (int j = t; j < cnt; j += 256) {
        int a = (int)buf[j].w - loA;
        arr[lo + scanA_[a] + (int)rnk[j]] = buf[j];   // scattered but L2-hot region
    }
}

// ============ phase B: one wave per atom (unchanged) ============
__global__ __launch_bounds__(256) void phaseB_kernel(
    const uint4* __restrict__ ang_rec, const int* __restrict__ ang_offsets,
    const uint4* __restrict__ edata,
    const uint4* __restrict__ rad_pay, const int* __restrict__ rad_offsets,
    const int* __restrict__ species,
    float* __restrict__ out, int n_atoms)
{
    __shared__ uint4 sh[4][256];      // 4KB per wave, wave-private
    int wid  = (blockIdx.x << 2) + (threadIdx.x >> 6);
    int lane = threadIdx.x & 63;
    uint4* my = sh[threadIdx.x >> 6];

    if (wid < n_atoms) {
        // ---------------- angular (MFMA) ----------------
        int atom = wid;
        int beg = ang_offsets[atom];
        int end = ang_offsets[atom + 1];
        int m  = lane & 15;
        int g4 = lane >> 4;
        const _Float16* hl = (const _Float16*)my;
        f32x4 acc = {0.f, 0.f, 0.f, 0.f};

        for (int base = beg; base < end; base += 64) {
            int idx = base + lane;
            unsigned q[16];
            if (idx < end) {
                uint4 pr = ang_rec[idx];
                int e1 = (int)pr.x;
                int e2 = (int)pr.y;
                float ang = __uint_as_float(pr.z);
                uint4 r1 = edata[e1];
                uint4 r2 = edata[e2];
                float d12 = 0.5f * (__uint_as_float(r1.x) + __uint_as_float(r2.x));
                float swp = 2.0f * __uint_as_float(r1.y) * __uint_as_float(r2.y);
                float2 v1a = unpack2(r1.z), v1b = unpack2(r1.w);
                float2 v2a = unpack2(r2.z), v2b = unpack2(r2.w);
                float vp[4] = {v1a.x + v2a.x, v1a.y + v2a.y, v1b.x + v2b.x, v1b.y + v2b.y};
                float vm[4] = {v1a.x * v2a.x, v1a.y * v2a.y, v1b.x * v2b.x, v1b.y * v2b.y};

                float sa, ca;
                __sincosf(ang, &sa, &ca);
                const float czv[4] = { 0.92387953f,  0.38268343f, -0.38268343f, -0.92387953f };
                const float szv[4] = { 0.38268343f,  0.92387953f,  0.92387953f,  0.38268343f };
                float f1v[4];
                #pragma unroll
                for (int z = 0; z < 4; ++z) {
                    float y = 0.5f + 0.5f * (ca * czv[z] + sa * szv[z]);
                    float y2 = y * y, y4 = y2 * y2, y8 = y4 * y4, y16 = y8 * y8;
                    f1v[z] = y16 * y16;
                }
                float f2sv[4];
                #pragma unroll
                for (int a = 0; a < 4; ++a) {
                    float x = d12 - (0.8f + 0.675f * (float)a);
                    f2sv[a] = swp * __expf(-8.0f * x * x);
                }
                #pragma unroll
                for (int a = 0; a < 4; ++a) {
                    q[a * 2 + 0] = pack2(f2sv[a] * f1v[0], f2sv[a] * f1v[1]);
                    q[a * 2 + 1] = pack2(f2sv[a] * f1v[2], f2sv[a] * f1v[3]);
                }
                #pragma unroll
                for (int i2 = 0; i2 < 4; ++i2) {
                    q[8 + i2 * 2 + 0] = pack2(vp[i2] * vm[0], vp[i2] * vm[1]);
                    q[8 + i2 * 2 + 1] = pack2(vp[i2] * vm[2], vp[i2] * vm[3]);
                }
            } else {
                #pragma unroll
                for (int k = 0; k < 16; ++k) q[k] = 0u;
            }
            my[lane * 4 + 0] = make_uint4(q[0],  q[1],  q[2],  q[3]);
            my[lane * 4 + 1] = make_uint4(q[4],  q[5],  q[6],  q[7]);
            my[lane * 4 + 2] = make_uint4(q[8],  q[9],  q[10], q[11]);
            my[lane * 4 + 3] = make_uint4(q[12], q[13], q[14], q[15]);
            asm volatile("s_waitcnt lgkmcnt(0)" ::: "memory");

            int cnt = min(64, end - base);
            {
                f16x8 wf, uf;
                #pragma unroll
                for (int i = 0; i < 8; ++i) {
                    int row = (g4 << 3) + i;
                    wf[i] = hl[row * 32 + m];
                    uf[i] = hl[row * 32 + 16 + m];
                }
                acc = __builtin_amdgcn_mfma_f32_16x16x32_f16(wf, uf, acc, 0, 0, 0);
            }
            if (cnt > 32) {
                f16x8 wf, uf;
                #pragma unroll
                for (int i = 0; i < 8; ++i) {
                    int row = 32 + (g4 << 3) + i;
                    wf[i] = hl[row * 32 + m];
                    uf[i] = hl[row * 32 + 16 + m];
                }
                acc = __builtin_amdgcn_mfma_f32_16x16x32_f16(wf, uf, acc, 0, 0, 0);
            }
            asm volatile("s_waitcnt lgkmcnt(0)" ::: "memory");
        }
        // C/D layout (m89-verified): col = lane&15, row = (lane>>4)*4 + reg
        float* orow = out + (size_t)atom * NCOLS + ANG_OFF;
        #pragma unroll
        for (int r = 0; r < 4; ++r)
            orow[(g4 * 4 + r) * 16 + m] = acc[r];
        return;
    }

    // ---------------- radial + onehot ----------------
    int atom = wid - n_atoms;
    if (atom >= n_atoms) return;
    int beg = rad_offsets[atom];
    int end = rad_offsets[atom + 1];
    int r = lane >> 2, k = lane & 3;
    float shift = 0.8f + 0.275f * (float)r;
    float acc = 0.0f;
    for (int base = beg; base < end; base += 64) {
        int idx = base + lane;
        if (idx < end) my[lane] = rad_pay[idx];
        asm volatile("s_waitcnt lgkmcnt(0)" ::: "memory");
        int cnt = min(64, end - base);
        for (int e = 0; e < cnt; ++e) {
            uint4 rec = my[e];
            float d = __uint_as_float(rec.x);
            float2 f01 = unpack2(rec.y);
            float2 f23 = unpack2(rec.z);
            float pv = (k == 0) ? f01.x : (k == 1) ? f01.y : (k == 2) ? f23.x : f23.y;
            float x = d - shift;
            acc += __expf(-16.0f * x * x) * pv;
        }
        asm volatile("s_waitcnt lgkmcnt(0)" ::: "memory");
    }
    size_t rowbase = (size_t)atom * NCOLS;
    out[rowbase + RAD_OFF + lane] = acc;
    int sp = species[atom];
    out[rowbase + lane] = (lane == sp) ? 1.0f : 0.0f;
    if (lane < 23) out[rowbase + 64 + lane] = ((64 + lane) == sp) ? 1.0f : 0.0f;
}

extern "C" void kernel_launch(void* const* d_in, const int* in_sizes, int n_in,
                              void* d_out, int out_size, void* d_ws, size_t ws_size,
                              hipStream_t stream) {
    const int*   species      = (const int*)  d_in[0];
    const float* distances    = (const float*)d_in[1];
    const float* switch_      = (const float*)d_in[2];
    const int*   edge_src     = (const int*)  d_in[3];
    const int*   edge_dst     = (const int*)  d_in[4];
    const float* ang_angles   = (const float*)d_in[5];
    const float* ang_dist     = (const float*)d_in[6];
    const float* ang_switch   = (const float*)d_in[7];
    const int*   ang_edge_dst = (const int*)  d_in[8];
    const int*   angle_src    = (const int*)  d_in[9];
    const int*   angle_dst    = (const int*)  d_in[10];
    const int*   central_atom = (const int*)  d_in[11];
    const float4* valence     = (const float4*)d_in[12];

    float* out = (float*)d_out;

    const int n_atoms     = in_sizes[0];
    const int n_edges     = in_sizes[1];
    const int n_ang_edges = in_sizes[6];
    const int n_pairs     = in_sizes[5];

    const int nbkt   = (n_atoms + WB - 1) / WB;       // 625 (<= MAXBKT)
    const int nt_rad = (n_edges + T1 - 1) / T1;       // 209
    const int nt_ang = (n_pairs + T1 - 1) / T1;       // 183

    // ---- workspace layout (16B-aligned), total ~= 23.3 MB ----
    char* ws = (char*)d_ws;
    size_t off = 0;
    auto alloc = [&](size_t bytes) -> void* {
        void* p = ws + off;
        off = (off + bytes + 15) & ~(size_t)15;
        return p;
    };
    uint4*  arr_rad     = (uint4*) alloc((size_t)n_edges * 16);                     // 10.24 MB
    uint4*  arr_ang     = (uint4*) alloc((size_t)n_pairs * 16);                     //  8.96 MB
    uint4*  edata       = (uint4*) alloc((size_t)n_ang_edges * 16);                 //  2.56 MB
    int*    tileHist    = (int*)   alloc((size_t)(nt_rad + nt_ang) * nbkt * 4);     //  0.98 MB
    int*    bktTotals   = (int*)   alloc((size_t)2 * MAXBKT * sizeof(int));
    int*    bktBase     = (int*)   alloc((size_t)2 * (MAXBKT + 1) * sizeof(int));
    float4* val_atom    = (float4*)alloc((size_t)n_atoms * sizeof(float4));         //  0.32 MB
    int*    rad_offsets = (int*)   alloc((size_t)(n_atoms + 1) * sizeof(int));
    int*    ang_offsets = (int*)   alloc((size_t)(n_atoms + 1) * sizeof(int));

    init_kernel<<<(n_atoms + 255) / 256, 256, 0, stream>>>(
        species, valence, val_atom, n_atoms);

    int nb_edata = (n_ang_edges + 2559) / 2560;
    pass0_kernel<<<nt_rad + nt_ang + nb_edata, 256, 0, stream>>>(
        edge_src, central_atom, ang_dist, ang_switch, ang_edge_dst, val_atom,
        tileHist, edata, n_edges, n_pairs, n_ang_edges, nbkt, nt_rad, nt_ang);

    scanA_kernel<<<(2 * nbkt + 3) / 4, 256, 0, stream>>>(
        tileHist, bktTotals, nt_rad, nt_ang, nbkt);

    scanB_kernel<<<2, 1024, 0, stream>>>(bktTotals, bktBase, nbkt);

    pass1_kernel<<<nt_rad + nt_ang, 256, 0, stream>>>(
        distances, switch_, edge_src, edge_dst,
        ang_angles, angle_src, angle_dst, central_atom,
        val_atom, tileHist, bktBase, arr_rad, arr_ang,
        n_edges, n_pairs, nbkt, nt_rad);

    pass2_kernel<<<2 * nbkt, 256, 0, stream>>>(
        arr_rad, arr_ang, bktBase, rad_offsets, ang_offsets, nbkt, n_atoms);

    int nb_B = (2 * n_atoms + 3) / 4;    // 4 waves/block, 1 atom per wave
    phaseB_kernel<<<nb_B, 256, 0, stream>>>(
        arr_ang, ang_offsets, edata, arr_rad, rad_offsets, species, out, n_atoms);
}

// Round 13
// 78.895 us; speedup vs baseline: 1.9846x; 1.1422x over previous
//
#include <hip/hip_runtime.h>
#include <hip/hip_fp16.h>
#include <math.h>

// ---- problem constants (match reference) ----
#define NCOLS   407
#define RAD_OFF 87
#define ANG_OFF 151
#define T1      3072    // items per sort tile
#define WB      32      // atoms per bucket (bucket = atom>>5)
#define MAXBKT  640     // max buckets supported (n_atoms <= 20480)
#define CAP2    3008    // pass2 per-bucket LDS capacity (mean ~1000, +60 sigma)

// shiftR[r] = 0.8 + r*0.275  (r=0..15)
// shiftA[a] = 0.8 + a*0.675  (a=0..3)
// shiftZ[z] = pi/8 + z*pi/4  (z=0..3)

typedef __attribute__((ext_vector_type(8))) _Float16 f16x8;
typedef __attribute__((ext_vector_type(4))) float    f32x4;

static __device__ inline unsigned pack2(float a, float b) {
    __half2 h = __floats2half2_rn(a, b);
    return *reinterpret_cast<unsigned*>(&h);
}
static __device__ inline float2 unpack2(unsigned u) {
    __half2 h = *reinterpret_cast<__half2*>(&u);
    return __half22float2(h);
}

// ============ init: per-atom valence table ============
__global__ __launch_bounds__(256) void init_kernel(const int* __restrict__ species,
                                                   const float4* __restrict__ valence,
                                                   float4* __restrict__ val_atom,
                                                   int n_atoms) {
    int idx = blockIdx.x * 256 + threadIdx.x;
    if (idx < n_atoms) val_atom[idx] = valence[species[idx]];
}

// ============ pass0: per-tile bucket histogram (keys only) + edata build ============
__global__ __launch_bounds__(256) void pass0_kernel(const int* __restrict__ esrc,
                                                    const int* __restrict__ central,
                                                    const float* __restrict__ ang_dist,
                                                    const float* __restrict__ ang_sw,
                                                    const int* __restrict__ ang_edge_dst,
                                                    const float4* __restrict__ val_atom,
                                                    int* __restrict__ tileHist,
                                                    uint4* __restrict__ edata,
                                                    int n_edges, int n_pairs, int n_ang_edges,
                                                    int nbkt, int nt_rad, int nt_ang) {
    int bid = blockIdx.x;
    int t = threadIdx.x;

    if (bid < nt_rad + nt_ang) {
        __shared__ int lh[MAXBKT];
        int is_ang = bid >= nt_rad;
        const int* key = is_ang ? central : esrc;
        int n   = is_ang ? n_pairs : n_edges;
        int off = (is_ang ? bid - nt_rad : bid) * T1;
        for (int b = t; b < nbkt; b += 256) lh[b] = 0;
        __syncthreads();
        #pragma unroll
        for (int k = 0; k < T1 / 256; ++k) {
            int i = off + k * 256 + t;
            if (i < n) atomicAdd(&lh[key[i] >> 5], 1);
        }
        __syncthreads();
        int* row = tileHist + (size_t)bid * nbkt;
        for (int b = t; b < nbkt; b += 256) row[b] = lh[b];
        return;
    }

    // ---- edata blocks: 2560 edges each ----
    int i = (bid - nt_rad - nt_ang) * 2560 + t;
    #pragma unroll
    for (int k = 0; k < 10; ++k, i += 256) {
        if (i < n_ang_edges) {
            float4 v = val_atom[ang_edge_dst[i]];
            uint4 r;
            r.x = __float_as_uint(ang_dist[i]);
            r.y = __float_as_uint(ang_sw[i]);
            r.z = pack2(v.x, v.y);
            r.w = pack2(v.z, v.w);
            edata[i] = r;
        }
    }
}

// ============ scanA: one WAVE per (graph,bucket): in-place local prefix + totals ============
__global__ __launch_bounds__(256) void scanA_kernel(int* __restrict__ tileHist,
                                                    int* __restrict__ bktTotals,
                                                    int nt_rad, int nt_ang, int nbkt) {
    int wid  = blockIdx.x * 4 + (threadIdx.x >> 6);
    int lane = threadIdx.x & 63;
    if (wid >= 2 * nbkt) return;
    int g = wid >= nbkt;
    int b = g ? wid - nbkt : wid;
    int* th = tileHist + (g ? (size_t)nt_rad * nbkt : 0);
    int nt = g ? nt_ang : nt_rad;
    int run = 0;
    for (int k0 = 0; k0 < nt; k0 += 64) {
        int k = k0 + lane;
        int v = (k < nt) ? th[(size_t)k * nbkt + b] : 0;
        int s = v;
        #pragma unroll
        for (int o = 1; o < 64; o <<= 1) {
            int u = __shfl_up(s, o, 64);
            if (lane >= o) s += u;
        }
        if (k < nt) th[(size_t)k * nbkt + b] = run + s - v;   // bucket-local exclusive
        run += __shfl(s, 63, 64);
    }
    if (lane == 0) bktTotals[g * MAXBKT + b] = run;
}

// ============ scanB: exclusive scan over buckets -> bktBase ============
__global__ __launch_bounds__(1024) void scanB_kernel(const int* __restrict__ bktTotals,
                                                     int* __restrict__ bktBase, int nbkt) {
    int g = blockIdx.x;
    const int* tot = bktTotals + g * MAXBKT;
    int* bb = bktBase + g * (MAXBKT + 1);
    __shared__ int part[1024];
    int t = threadIdx.x;
    int v = (t < nbkt) ? tot[t] : 0;
    part[t] = v;
    __syncthreads();
    for (int o = 1; o < 1024; o <<= 1) {
        int u = (t >= o) ? part[t - o] : 0;
        __syncthreads();
        part[t] += u;
        __syncthreads();
    }
    if (t < nbkt) bb[t] = part[t] - v;
    if (t == nbkt - 1) bb[nbkt] = part[t];
}

// ============ pass1: compute records + LDS bucket-reorder + COALESCED store ============
__global__ __launch_bounds__(256) void pass1_kernel(
    const float* __restrict__ dist, const float* __restrict__ sw,
    const int* __restrict__ esrc, const int* __restrict__ edst,
    const float* __restrict__ ang_angles,
    const int* __restrict__ psrc, const int* __restrict__ pdst,
    const int* __restrict__ central,
    const float4* __restrict__ val_atom,
    const int* __restrict__ tileHist, const int* __restrict__ bktBase,
    uint4* __restrict__ arr_rad, uint4* __restrict__ arr_ang,
    int n_edges, int n_pairs, int nbkt, int nt_rad)
{
    __shared__ uint4 buf[T1];        // 48 KB
    __shared__ int   dst[T1];        // 12 KB
    __shared__ int   lh[MAXBKT];     // counts -> exclusive scan
    __shared__ int   gb[MAXBKT];     // global run bases for this tile
    __shared__ int   sc[256];

    int bid = blockIdx.x;
    int t = threadIdx.x;
    int is_ang = bid >= nt_rad;
    const int* key = is_ang ? central : esrc;
    int n   = is_ang ? n_pairs : n_edges;
    int off = (is_ang ? bid - nt_rad : bid) * T1;
    int cnt = min(T1, n - off);
    uint4* arr = is_ang ? arr_ang : arr_rad;
    const int* row = tileHist + (size_t)bid * nbkt;
    const int* bb  = bktBase + is_ang * (MAXBKT + 1);

    for (int b = t; b < nbkt; b += 256) { lh[b] = 0; gb[b] = row[b] + bb[b]; }
    __syncthreads();

    // loop 1: ranks
    int meta[T1 / 256];              // b*4096 + rank
    #pragma unroll
    for (int k = 0; k < T1 / 256; ++k) {
        int i = off + k * 256 + t;
        meta[k] = -1;
        if (i < n) {
            int b = key[i] >> 5;
            int r = atomicAdd(&lh[b], 1);
            meta[k] = (b << 12) | r;
        }
    }
    __syncthreads();

    // exclusive scan of lh[0..nbkt)
    {
        int ch = (nbkt + 255) >> 8;
        int vals[4];
        int lo = t * ch, s = 0;
        for (int k = 0; k < ch; ++k) {
            int idx = lo + k;
            int v = (idx < nbkt) ? lh[idx] : 0;
            vals[k] = v; s += v;
        }
        sc[t] = s;
        __syncthreads();
        for (int o = 1; o < 256; o <<= 1) {
            int v = (t >= o) ? sc[t - o] : 0;
            __syncthreads();
            sc[t] += v;
            __syncthreads();
        }
        int run = sc[t] - s;
        for (int k = 0; k < ch; ++k) {
            int idx = lo + k;
            if (idx < nbkt) lh[idx] = run;
            run += vals[k];
        }
        __syncthreads();
    }

    // loop 2: build records, place into LDS at bucket-sorted position
    #pragma unroll
    for (int k = 0; k < T1 / 256; ++k) {
        if (meta[k] < 0) continue;
        int i = off + k * 256 + t;
        int b = meta[k] >> 12, r = meta[k] & 4095;
        uint4 rec;
        if (!is_ang) {
            float d  = dist[i];
            float ps = 0.25f * sw[i];
            float4 v = val_atom[edst[i]];
            rec.x = __float_as_uint(d);
            rec.y = pack2(ps * v.x, ps * v.y);
            rec.z = pack2(ps * v.z, ps * v.w);
            rec.w = (unsigned)esrc[i];
        } else {
            rec.x = (unsigned)psrc[i];
            rec.y = (unsigned)pdst[i];
            rec.z = __float_as_uint(ang_angles[i]);
            rec.w = (unsigned)central[i];
        }
        int pos = lh[b] + r;
        buf[pos] = rec;
        dst[pos] = gb[b] + r;        // consecutive within each bucket run
    }
    __syncthreads();

    // loop 3: coalesced writer (dst consecutive within runs)
    #pragma unroll
    for (int k = 0; k < T1 / 256; ++k) {
        int j = k * 256 + t;
        if (j < cnt) arr[dst[j]] = buf[j];
    }
}

// ============ pass2: per-bucket in-place sort by atom + offsets ============
__global__ __launch_bounds__(256) void pass2_kernel(uint4* __restrict__ arr_rad,
                                                    uint4* __restrict__ arr_ang,
                                                    const int* __restrict__ bktBase,
                                                    int* __restrict__ rad_offsets,
                                                    int* __restrict__ ang_offsets,
                                                    int nbkt, int n_atoms) {
    __shared__ uint4  buf[CAP2];     // 48.1 KB
    __shared__ unsigned short rnk[CAP2];
    __shared__ int lh[WB];
    __shared__ int scanA_[WB + 1];

    int bid = blockIdx.x;
    int t = threadIdx.x;
    int g = bid >= nbkt;
    int b = g ? bid - nbkt : bid;
    const int* bb = bktBase + g * (MAXBKT + 1);
    int lo = bb[b], hi = bb[b + 1];
    int cnt = hi - lo;
    uint4* arr = g ? arr_ang : arr_rad;
    int* offsets = g ? ang_offsets : rad_offsets;
    int loA = b << 5;

    if (t < WB) lh[t] = 0;
    __syncthreads();
    for (int j = t; j < cnt; j += 256) {
        uint4 r = arr[lo + j];
        buf[j] = r;
        int a = (int)r.w - loA;
        rnk[j] = (unsigned short)atomicAdd(&lh[a], 1);
    }
    __syncthreads();
    if (t == 0) {
        int run = 0;
        for (int a = 0; a < WB; ++a) { scanA_[a] = run; run += lh[a]; }
        scanA_[WB] = run;
    }
    __syncthreads();
    if (t < WB && loA + t < n_atoms) offsets[loA + t] = lo + scanA_[t];
    if (t == 0 && b == nbkt - 1) offsets[n_atoms] = bb[nbkt];
    for (int j = t; j < cnt; j += 256) {
        int a = (int)buf[j].w - loA;
        arr[lo + scanA_[a] + (int)rnk[j]] = buf[j];   // scattered but L2-hot region
    }
}

// ============ phase B: one wave per atom ============
// waves [0, n_atoms): angular MFMA; waves [n_atoms, 2n): radial MFMA + onehot
__global__ __launch_bounds__(256) void phaseB_kernel(
    const uint4* __restrict__ ang_rec, const int* __restrict__ ang_offsets,
    const uint4* __restrict__ edata,
    const uint4* __restrict__ rad_pay, const int* __restrict__ rad_offsets,
    const int* __restrict__ species,
    float* __restrict__ out, int n_atoms)
{
    __shared__ uint4 sh[4][256];      // 4KB per wave, wave-private
    int wid  = (blockIdx.x << 2) + (threadIdx.x >> 6);
    int lane = threadIdx.x & 63;
    uint4* my = sh[threadIdx.x >> 6];

    if (wid < n_atoms) {
        // ---------------- angular (MFMA) ----------------
        int atom = wid;
        int beg = ang_offsets[atom];
        int end = ang_offsets[atom + 1];
        int m  = lane & 15;
        int g4 = lane >> 4;
        const _Float16* hl = (const _Float16*)my;
        f32x4 acc = {0.f, 0.f, 0.f, 0.f};

        for (int base = beg; base < end; base += 64) {
            int idx = base + lane;
            unsigned q[16];
            if (idx < end) {
                uint4 pr = ang_rec[idx];
                int e1 = (int)pr.x;
                int e2 = (int)pr.y;
                float ang = __uint_as_float(pr.z);
                uint4 r1 = edata[e1];
                uint4 r2 = edata[e2];
                float d12 = 0.5f * (__uint_as_float(r1.x) + __uint_as_float(r2.x));
                float swp = 2.0f * __uint_as_float(r1.y) * __uint_as_float(r2.y);
                float2 v1a = unpack2(r1.z), v1b = unpack2(r1.w);
                float2 v2a = unpack2(r2.z), v2b = unpack2(r2.w);
                float vp[4] = {v1a.x + v2a.x, v1a.y + v2a.y, v1b.x + v2b.x, v1b.y + v2b.y};
                float vm[4] = {v1a.x * v2a.x, v1a.y * v2a.y, v1b.x * v2b.x, v1b.y * v2b.y};

                float sa, ca;
                __sincosf(ang, &sa, &ca);
                const float czv[4] = { 0.92387953f,  0.38268343f, -0.38268343f, -0.92387953f };
                const float szv[4] = { 0.38268343f,  0.92387953f,  0.92387953f,  0.38268343f };
                float f1v[4];
                #pragma unroll
                for (int z = 0; z < 4; ++z) {
                    float y = 0.5f + 0.5f * (ca * czv[z] + sa * szv[z]);
                    float y2 = y * y, y4 = y2 * y2, y8 = y4 * y4, y16 = y8 * y8;
                    f1v[z] = y16 * y16;
                }
                float f2sv[4];
                #pragma unroll
                for (int a = 0; a < 4; ++a) {
                    float x = d12 - (0.8f + 0.675f * (float)a);
                    f2sv[a] = swp * __expf(-8.0f * x * x);
                }
                #pragma unroll
                for (int a = 0; a < 4; ++a) {
                    q[a * 2 + 0] = pack2(f2sv[a] * f1v[0], f2sv[a] * f1v[1]);
                    q[a * 2 + 1] = pack2(f2sv[a] * f1v[2], f2sv[a] * f1v[3]);
                }
                #pragma unroll
                for (int i2 = 0; i2 < 4; ++i2) {
                    q[8 + i2 * 2 + 0] = pack2(vp[i2] * vm[0], vp[i2] * vm[1]);
                    q[8 + i2 * 2 + 1] = pack2(vp[i2] * vm[2], vp[i2] * vm[3]);
                }
            } else {
                #pragma unroll
                for (int k = 0; k < 16; ++k) q[k] = 0u;
            }
            my[lane * 4 + 0] = make_uint4(q[0],  q[1],  q[2],  q[3]);
            my[lane * 4 + 1] = make_uint4(q[4],  q[5],  q[6],  q[7]);
            my[lane * 4 + 2] = make_uint4(q[8],  q[9],  q[10], q[11]);
            my[lane * 4 + 3] = make_uint4(q[12], q[13], q[14], q[15]);
            asm volatile("s_waitcnt lgkmcnt(0)" ::: "memory");

            int cnt = min(64, end - base);
            {
                f16x8 wf, uf;
                #pragma unroll
                for (int i = 0; i < 8; ++i) {
                    int row = (g4 << 3) + i;
                    wf[i] = hl[row * 32 + m];
                    uf[i] = hl[row * 32 + 16 + m];
                }
                acc = __builtin_amdgcn_mfma_f32_16x16x32_f16(wf, uf, acc, 0, 0, 0);
            }
            if (cnt > 32) {
                f16x8 wf, uf;
                #pragma unroll
                for (int i = 0; i < 8; ++i) {
                    int row = 32 + (g4 << 3) + i;
                    wf[i] = hl[row * 32 + m];
                    uf[i] = hl[row * 32 + 16 + m];
                }
                acc = __builtin_amdgcn_mfma_f32_16x16x32_f16(wf, uf, acc, 0, 0, 0);
            }
            asm volatile("s_waitcnt lgkmcnt(0)" ::: "memory");
        }
        // C/D layout (m89-verified): col = lane&15, row = (lane>>4)*4 + reg
        float* orow = out + (size_t)atom * NCOLS + ANG_OFF;
        #pragma unroll
        for (int r = 0; r < 4; ++r)
            orow[(g4 * 4 + r) * 16 + m] = acc[r];
        return;
    }

    // ---------------- radial (MFMA) + onehot ----------------
    // out[r][k] = sum_e exp(-16(d_e - shift_r)^2) * pv_k(e): 16x4 GEMM over edges.
    // Same verified fragment indexing as angular: A[m][k], B[k][m(<4)], C row=(g4*4+reg).
    int atom = wid - n_atoms;
    if (atom >= n_atoms) return;
    int beg = rad_offsets[atom];
    int end = rad_offsets[atom + 1];
    int m  = lane & 15;
    int g4 = lane >> 4;
    const _Float16* hl = (const _Float16*)my;   // rec = 8 halves: [d_lo,d_hi,pv0..3,0,0]
    const float*    fl = (const float*)my;
    float shiftm = 0.8f + 0.275f * (float)m;
    f32x4 acc = {0.f, 0.f, 0.f, 0.f};

    for (int base = beg; base < end; base += 64) {
        int idx = base + lane;
        my[lane] = (idx < end) ? rad_pay[idx] : make_uint4(0u, 0u, 0u, 0u);  // zero-pad tail
        asm volatile("s_waitcnt lgkmcnt(0)" ::: "memory");

        int cnt = min(64, end - base);
        {
            f16x8 wf, uf;
            #pragma unroll
            for (int i = 0; i < 8; ++i) {
                int k = (g4 << 3) + i;               // edges 0..31
                float d = fl[k * 4];                  // broadcast b32
                float x = d - shiftm;
                wf[i] = (_Float16)__expf(-16.0f * x * x);
                uf[i] = (m < 4) ? hl[k * 8 + 2 + m] : (_Float16)0.0f;
            }
            acc = __builtin_amdgcn_mfma_f32_16x16x32_f16(wf, uf, acc, 0, 0, 0);
        }
        if (cnt > 32) {
            f16x8 wf, uf;
            #pragma unroll
            for (int i = 0; i < 8; ++i) {
                int k = 32 + (g4 << 3) + i;          // edges 32..63
                float d = fl[k * 4];
                float x = d - shiftm;
                wf[i] = (_Float16)__expf(-16.0f * x * x);
                uf[i] = (m < 4) ? hl[k * 8 + 2 + m] : (_Float16)0.0f;
            }
            acc = __builtin_amdgcn_mfma_f32_16x16x32_f16(wf, uf, acc, 0, 0, 0);
        }
        asm volatile("s_waitcnt lgkmcnt(0)" ::: "memory");
    }
    size_t rowbase = (size_t)atom * NCOLS;
    if (m < 4) {
        #pragma unroll
        for (int r = 0; r < 4; ++r)
            out[rowbase + RAD_OFF + (g4 * 4 + r) * 4 + m] = acc[r];
    }
    int sp = species[atom];
    out[rowbase + lane] = (lane == sp) ? 1.0f : 0.0f;
    if (lane < 23) out[rowbase + 64 + lane] = ((64 + lane) == sp) ? 1.0f : 0.0f;
}

extern "C" void kernel_launch(void* const* d_in, const int* in_sizes, int n_in,
                              void* d_out, int out_size, void* d_ws, size_t ws_size,
                              hipStream_t stream) {
    const int*   species      = (const int*)  d_in[0];
    const float* distances    = (const float*)d_in[1];
    const float* switch_      = (const float*)d_in[2];
    const int*   edge_src     = (const int*)  d_in[3];
    const int*   edge_dst     = (const int*)  d_in[4];
    const float* ang_angles   = (const float*)d_in[5];
    const float* ang_dist     = (const float*)d_in[6];
    const float* ang_switch   = (const float*)d_in[7];
    const int*   ang_edge_dst = (const int*)  d_in[8];
    const int*   angle_src    = (const int*)  d_in[9];
    const int*   angle_dst    = (const int*)  d_in[10];
    const int*   central_atom = (const int*)  d_in[11];
    const float4* valence     = (const float4*)d_in[12];

    float* out = (float*)d_out;

    const int n_atoms     = in_sizes[0];
    const int n_edges     = in_sizes[1];
    const int n_ang_edges = in_sizes[6];
    const int n_pairs     = in_sizes[5];

    const int nbkt   = (n_atoms + WB - 1) / WB;       // 625 (<= MAXBKT)
    const int nt_rad = (n_edges + T1 - 1) / T1;       // 209
    const int nt_ang = (n_pairs + T1 - 1) / T1;       // 183

    // ---- workspace layout (16B-aligned), total ~= 23.3 MB ----
    char* ws = (char*)d_ws;
    size_t off = 0;
    auto alloc = [&](size_t bytes) -> void* {
        void* p = ws + off;
        off = (off + bytes + 15) & ~(size_t)15;
        return p;
    };
    uint4*  arr_rad     = (uint4*) alloc((size_t)n_edges * 16);                     // 10.24 MB
    uint4*  arr_ang     = (uint4*) alloc((size_t)n_pairs * 16);                     //  8.96 MB
    uint4*  edata       = (uint4*) alloc((size_t)n_ang_edges * 16);                 //  2.56 MB
    int*    tileHist    = (int*)   alloc((size_t)(nt_rad + nt_ang) * nbkt * 4);     //  0.98 MB
    int*    bktTotals   = (int*)   alloc((size_t)2 * MAXBKT * sizeof(int));
    int*    bktBase     = (int*)   alloc((size_t)2 * (MAXBKT + 1) * sizeof(int));
    float4* val_atom    = (float4*)alloc((size_t)n_atoms * sizeof(float4));         //  0.32 MB
    int*    rad_offsets = (int*)   alloc((size_t)(n_atoms + 1) * sizeof(int));
    int*    ang_offsets = (int*)   alloc((size_t)(n_atoms + 1) * sizeof(int));

    init_kernel<<<(n_atoms + 255) / 256, 256, 0, stream>>>(
        species, valence, val_atom, n_atoms);

    int nb_edata = (n_ang_edges + 2559) / 2560;
    pass0_kernel<<<nt_rad + nt_ang + nb_edata, 256, 0, stream>>>(
        edge_src, central_atom, ang_dist, ang_switch, ang_edge_dst, val_atom,
        tileHist, edata, n_edges, n_pairs, n_ang_edges, nbkt, nt_rad, nt_ang);

    scanA_kernel<<<(2 * nbkt + 3) / 4, 256, 0, stream>>>(
        tileHist, bktTotals, nt_rad, nt_ang, nbkt);

    scanB_kernel<<<2, 1024, 0, stream>>>(bktTotals, bktBase, nbkt);

    pass1_kernel<<<nt_rad + nt_ang, 256, 0, stream>>>(
        distances, switch_, edge_src, edge_dst,
        ang_angles, angle_src, angle_dst, central_atom,
        val_atom, tileHist, bktBase, arr_rad, arr_ang,
        n_edges, n_pairs, nbkt, nt_rad);

    pass2_kernel<<<2 * nbkt, 256, 0, stream>>>(
        arr_rad, arr_ang, bktBase, rad_offsets, ang_offsets, nbkt, n_atoms);

    int nb_B = (2 * n_atoms + 3) / 4;    // 4 waves/block, 1 atom per wave
    phaseB_kernel<<<nb_B, 256, 0, stream>>>(
        arr_ang, ang_offsets, edata, arr_rad, rad_offsets, species, out, n_atoms);
}